// Round 13
// baseline (257.472 us; speedup 1.0000x reference)
//
#include <hip/hip_runtime.h>

#define BROWS 65536
#define DDIM 256
#define MCODES 1024
// Margin budget (xn-free f16 epilogue vs reference):
//   deterministic ref rounding noise <= 2*ulp(256) = 6.1e-5
//   f16 1-pass dot-pair noise sigma ~ 2.5e-5  ->  3e-4 gives ~10 sigma slack.
// Measured (R5): ~2000 flagged rows at 3e-4 (WRITE_SIZE 2080KB).
#define FLAG_MARGIN 3e-4f
#define RGRP 16
#define NPART 1024

typedef __attribute__((ext_vector_type(8))) _Float16 h8f16;   // f16x8 MFMA frag
typedef __attribute__((ext_vector_type(4))) float float4v;    // fp32x4 acc

__device__ inline unsigned short f2h_bits(float f) {
  union { _Float16 h; unsigned short u; } cv;
  cv.h = (_Float16)f;   // v_cvt_f16_f32, RNE
  return cv.u;
}

// ---------------- Kernel 1: emb-only prep (VALIDATED R8) ----------------
__global__ __launch_bounds__(256)
void prep_kernel(const float* __restrict__ emb,
                 float* __restrict__ enorm,
                 float* __restrict__ counts, int* __restrict__ nflag,
                 float* __restrict__ loss_extra,
                 unsigned short* __restrict__ eimg, float* __restrict__ embT) {
  int b = blockIdx.x;
  int tid = threadIdx.x;
  if (b < 64) {
    int t = b * 256 + tid;            // [0, 16384) -> 1024 emb rows x 16 lanes
    if (t < MCODES) counts[t] = 0.0f;
    if (t == 0) *nflag = 0;
    if (t < 2) loss_extra[t] = 0.0f;
    int row = t >> 4;
    int lane = t & 15;
    const float* p = emb + (size_t)row * DDIM;
    int half = (lane >> 3) & 1;
    int j = lane & 7;
    const float* q = p + half * 128 + j;
    float v = q[0];
    float acc = __fmul_rn(v, v);
    #pragma unroll
    for (int i = 1; i < 16; ++i) {
      v = q[i * 8];
      acc = __fadd_rn(acc, __fmul_rn(v, v));
    }
    float o;
    o = __shfl_xor(acc, 1, 64); acc = __fadd_rn(acc, o);
    o = __shfl_xor(acc, 2, 64); acc = __fadd_rn(acc, o);
    o = __shfl_xor(acc, 4, 64); acc = __fadd_rn(acc, o);
    o = __shfl_xor(acc, 8, 64); acc = __fadd_rn(acc, o);
    if (lane == 0) enorm[row] = acc;
  } else if (b < 192) {
    // f16 image chunk t (16B): lane=t&63, tile=(t>>6)&1, kstep=(t>>7)&7, cc=t>>10.
    // code = cc*32 + tile*16 + (lane&15); k = kstep*32 + (lane>>4)*8 + j.
    // stores f16(256*e) — exact pow2 scale; epilogue multiplies by -2^-7.
    int t = (b - 64) * 256 + tid;     // [0, 32768)
    int lane = t & 63;
    int tile = (t >> 6) & 1;
    int kstep = (t >> 7) & 7;
    int cc = t >> 10;
    int code = cc * 32 + tile * 16 + (lane & 15);
    int kb = kstep * 32 + (lane >> 4) * 8;
    const float* src = emb + (size_t)code * DDIM + kb;
    union { unsigned short u[8]; uint4 v; } out;
    #pragma unroll
    for (int jj = 0; jj < 8; ++jj) out.u[jj] = f2h_bits(src[jj] * 256.0f);
    ((uint4*)eimg)[t] = out.v;
  } else {
    int t = (b - 192) * 256 + tid;    // [0, 65536)
    int base = t * 4;
    int k = base >> 10;
    int m = base & 1023;
    float4 v;
    v.x = emb[(size_t)(m + 0) * DDIM + k];
    v.y = emb[(size_t)(m + 1) * DDIM + k];
    v.z = emb[(size_t)(m + 2) * DDIM + k];
    v.w = emb[(size_t)(m + 3) * DDIM + k];
    *(float4*)&embT[base] = v;
  }
}

// ---------------- Kernel 2: 1-pass f16 score — R12: BARRIER-FREE main loop ----------------
// R8-R11 postmortems: dur invariant to LDS traffic, rotation, tail, occupancy-mix ->
// last structural suspect is the 32 per-cc __syncthreads + vmcnt(0) drains coupling all
// waves to memory jitter (m97's barrier-drain stall). eimg is 512KB = L2-RESIDENT, so
// LDS staging is unnecessary (Common-mistake #7): each wave loads its 8 e-frags per tile
// DIRECTLY from L2 (1KB coalesced per ks). Main loop now has ZERO barriers — loads
// pipeline freely across cc, stalls covered by 16 waves/CU without sync coupling.
// Values bit-identical (same FMA/two-min; tie drift -> flagged -> rescore, validated R11).
__global__ __launch_bounds__(256, 4)
void score_kernel(const float* __restrict__ x, const float* __restrict__ emb,
                  const float* __restrict__ enorm_g,
                  const unsigned short* __restrict__ eimg,
                  int* __restrict__ idx_out, float* __restrict__ out_idxf,
                  float* __restrict__ qout, float* __restrict__ counts,
                  float* __restrict__ loss_part, float* __restrict__ np_part,
                  int* __restrict__ nflag, int* __restrict__ flist) {
  __shared__ float enorm_s[MCODES];
  __shared__ float sb1[2][64], sb2[2][64];
  __shared__ int si1[2][64];
  __shared__ int lcount;
  __shared__ int lbase;
  __shared__ int lrows[64];
  __shared__ int sidx[64];
  __shared__ unsigned char sflag[64];
  __shared__ float red[8];

  int tid = threadIdx.x;
  int w = tid >> 6;
  int lane = tid & 63;
  int quad = lane >> 4;
  int rowBase = blockIdx.x * 64;
  int waveRow = rowBase + (w & 1) * 32;   // rows this wave owns (32)
  int ct = w >> 1;                        // code-half this wave owns (16 codes)
  int rot = blockIdx.x & 31;              // per-block tile rotation (spreads L2 sets)

  if (tid == 0) lcount = 0;
  for (int i = tid; i < MCODES; i += 256) enorm_s[i] = enorm_g[i];

  // A-frag preload (validated layout): rows waveRow + rg*16 + (lane&15), k = ks*32 + quad*8 + j
  h8f16 xh[2][8];
  const float* xbase = x + (size_t)(waveRow + (lane & 15)) * DDIM + quad * 8;
  #pragma unroll
  for (int rg = 0; rg < 2; ++rg) {
    #pragma unroll
    for (int ks = 0; ks < 8; ++ks) {
      const float4* p = (const float4*)(xbase + rg * 16 * DDIM + ks * 32);
      float4 v0 = p[0], v1 = p[1];
      h8f16 h;
      h[0] = (_Float16)v0.x; h[1] = (_Float16)v0.y;
      h[2] = (_Float16)v0.z; h[3] = (_Float16)v0.w;
      h[4] = (_Float16)v1.x; h[5] = (_Float16)v1.y;
      h[6] = (_Float16)v1.z; h[7] = (_Float16)v1.w;
      xh[rg][ks] = h;
    }
  }

  float b1[2][4], b2[2][4];
  int i1[2][4];
  #pragma unroll
  for (int rg = 0; rg < 2; ++rg)
    #pragma unroll
    for (int reg = 0; reg < 4; ++reg) { b1[rg][reg] = 3.4e38f; b2[rg][reg] = 3.4e38f; i1[rg][reg] = 0; }

  __syncthreads();   // enorm_s visible; the ONLY barrier before the merge phase

  // per-wave e-frag base: this wave's code-half within each 16KB tile
  const unsigned short* ebase = eimg + ct * 512 + lane * 8;

  for (int cc = 0; cc < 32; ++cc) {
    int tc = (cc + rot) & 31;        // rotated tile index for this block
    const unsigned short* et = ebase + (size_t)tc * 8192;

    float4v acc0 = (float4v){0.f, 0.f, 0.f, 0.f};   // rg = 0
    float4v acc1 = (float4v){0.f, 0.f, 0.f, 0.f};   // rg = 1
    #pragma unroll
    for (int ks = 0; ks < 8; ++ks) {
      h8f16 e = *(const h8f16*)(et + ks * 1024);    // direct L2 load, 1KB/wave coalesced
      acc0 = __builtin_amdgcn_mfma_f32_16x16x32_f16(xh[0][ks], e, acc0, 0, 0, 0);
      acc1 = __builtin_amdgcn_mfma_f32_16x16x32_f16(xh[1][ks], e, acc1, 0, 0, 0);
    }

    int m = tc * 32 + ct * 16 + (lane & 15);
    float en = enorm_s[m];
    #pragma unroll
    for (int rg = 0; rg < 2; ++rg)
      #pragma unroll
      for (int reg = 0; reg < 4; ++reg) {
        float av = rg ? acc1[reg] : acc0[reg];
        float s = __fadd_rn(en, __fmul_rn(-0.0078125f, av));   // -2*dot = acc * -2^-7, exact scale
        // branchless two-min (value-exact, validated R11)
        float nb1 = fminf(s, b1[rg][reg]);
        b2[rg][reg] = fminf(b2[rg][reg], fmaxf(s, b1[rg][reg]));
        i1[rg][reg] = (s < b1[rg][reg]) ? m : i1[rg][reg];
        b1[rg][reg] = nb1;
      }
  }

  // cross-lane argmin over the 16 cols of this wave's code-half (verbatim two-min merge)
  #pragma unroll
  for (int off = 1; off < 16; off <<= 1) {
    #pragma unroll
    for (int rg = 0; rg < 2; ++rg)
      #pragma unroll
      for (int reg = 0; reg < 4; ++reg) {
        float ob1 = __shfl_xor(b1[rg][reg], off, 64);
        float ob2 = __shfl_xor(b2[rg][reg], off, 64);
        int oi = __shfl_xor(i1[rg][reg], off, 64);
        float cb1 = b1[rg][reg], cb2 = b2[rg][reg];
        int ci = i1[rg][reg];
        float nb1, nb2; int ni;
        if (ob1 < cb1)      { nb1 = ob1; ni = oi; nb2 = fminf(cb1, ob2); }
        else if (cb1 < ob1) { nb1 = cb1; ni = ci; nb2 = fminf(ob1, cb2); }
        else                { nb1 = cb1; ni = min(ci, oi); nb2 = cb1; }  // tie -> flag
        b1[rg][reg] = nb1; b2[rg][reg] = nb2; i1[rg][reg] = ni;
      }
  }

  // per-wave results -> LDS (row-half x code-half)
  if ((lane & 15) == 0) {
    #pragma unroll
    for (int rg = 0; rg < 2; ++rg)
      #pragma unroll
      for (int reg = 0; reg < 4; ++reg) {
        int lr = (w & 1) * 32 + rg * 16 + quad * 4 + reg;
        sb1[ct][lr] = b1[rg][reg];
        sb2[ct][lr] = b2[rg][reg];
        si1[ct][lr] = i1[rg][reg];
      }
  }
  __syncthreads();

  // cross-half merge (same two-min semantics: winner's b2 vs loser's b1; eq -> tie/flag)
  if (tid < 64) {
    float a1 = sb1[0][tid], a2 = sb2[0][tid];
    float c1 = sb1[1][tid], c2 = sb2[1][tid];
    int ia = si1[0][tid], ic = si1[1][tid];
    float f1, f2; int fi;
    if (a1 < c1)      { f1 = a1; fi = ia; f2 = fminf(a2, c1); }
    else if (c1 < a1) { f1 = c1; fi = ic; f2 = fminf(c2, a1); }
    else              { f1 = a1; fi = min(ia, ic); f2 = a1; }   // tie -> flag
    int row = rowBase + tid;
    idx_out[row] = fi;
    out_idxf[row] = (float)fi;
    sidx[tid] = fi;
    int fl = (__fadd_rn(f2, -f1) <= FLAG_MARGIN) ? 1 : 0;
    sflag[tid] = (unsigned char)fl;
    if (fl) {
      int pp = atomicAdd(&lcount, 1);
      lrows[pp] = row;
    }
  }
  __syncthreads();
  if (tid == 0 && lcount > 0) lbase = atomicAdd(nflag, lcount);
  __syncthreads();
  if (tid < lcount) flist[lbase + tid] = lrows[tid];

  // ---- fused gather (VALIDATED R9): ALL 4 waves, 16 sequential rows each.
  float lsum = 0.0f, nsum = 0.0f;
  for (int it = 0; it < 16; ++it) {
    int lr = w * 16 + it;
    int row = rowBase + lr;
    int id = sidx[lr];
    int fl = sflag[lr];
    float4 xv = ((const float4*)x)[(size_t)row * 64 + lane];
    float4 ev = ((const float4*)emb)[(size_t)id * 64 + lane];
    float4 q;
    q.x = __fadd_rn(xv.x, __fadd_rn(ev.x, -xv.x));
    q.y = __fadd_rn(xv.y, __fadd_rn(ev.y, -xv.y));
    q.z = __fadd_rn(xv.z, __fadd_rn(ev.z, -xv.z));
    q.w = __fadd_rn(xv.w, __fadd_rn(ev.w, -xv.w));
    ((float4*)qout)[(size_t)row * 64 + lane] = q;

    float d0 = xv.x - ev.x, d1 = xv.y - ev.y, d2 = xv.z - ev.z, d3 = xv.w - ev.w;
    float loc = d0 * d0 + d1 * d1 + d2 * d2 + d3 * d3;
    float la = fabsf(xv.x) + fabsf(xv.y) + fabsf(xv.z) + fabsf(xv.w);
    #pragma unroll
    for (int off = 32; off > 0; off >>= 1) {
      loc += __shfl_xor(loc, off, 64);
      la += __shfl_xor(la, off, 64);
    }
    if (lane == 0 && !fl) {
      float np = (la > 0.0f) ? 1.0f : 0.0f;
      lsum += (loc * (1.0f / 256.0f)) * np;
      nsum += np;
      atomicAdd(&counts[id], 1.0f);
    }
  }
  if (lane == 0) { red[w] = lsum; red[4 + w] = nsum; }
  __syncthreads();
  if (tid == 0) {
    loss_part[blockIdx.x] = (red[0] + red[1]) + (red[2] + red[3]);
    np_part[blockIdx.x] = (red[4] + red[5]) + (red[6] + red[7]);
  }
}

// ---------------- Kernel 3: latency-optimized exact fp32 rescore (VALIDATED R7/R8) ----------------
__global__ __launch_bounds__(256)
void rescore_kernel(const float* __restrict__ x, const float* __restrict__ emb,
                    const float* __restrict__ embT,
                    const float* __restrict__ enorm,
                    int* __restrict__ idx_out, float* __restrict__ out_idxf,
                    float* __restrict__ qout, float* __restrict__ counts,
                    float* __restrict__ loss_extra,
                    const int* __restrict__ nflag, const int* __restrict__ flist) {
  __shared__ float xs[RGRP][DDIM];
  __shared__ float xnr[RGRP];
  __shared__ int rown[RGRP];
  __shared__ int sbf[RGRP];
  __shared__ float rv[RGRP][256];
  __shared__ int ri[RGRP][256];
  int tid = threadIdx.x;
  int n = nflag[0];

  for (int g = blockIdx.x; g * RGRP < n; g += 1024) {
    int base = g * RGRP;
    int cnt = min(RGRP, n - base);
    __syncthreads();
    if (tid < RGRP) {
      int rr = flist[base + min(tid, cnt - 1)];
      rown[tid] = rr;
    }
    __syncthreads();
    #pragma unroll
    for (int r = 0; r < RGRP; ++r) xs[r][tid] = x[(size_t)rown[r] * DDIM + tid];
    __syncthreads();

    // local xnorm: group r=tid>>4, lane=tid&15 — EXACT association of the validated
    // norms kernel (16 strided squares serial, then shfl_xor 1,2,4,8).
    {
      int r = tid >> 4;
      int lane = tid & 15;
      int half = (lane >> 3) & 1;
      int j = lane & 7;
      const float* q = &xs[r][half * 128 + j];
      float v = q[0];
      float acc = __fmul_rn(v, v);
      #pragma unroll
      for (int i = 1; i < 16; ++i) {
        v = q[i * 8];
        acc = __fadd_rn(acc, __fmul_rn(v, v));
      }
      float o;
      o = __shfl_xor(acc, 1, 64); acc = __fadd_rn(acc, o);
      o = __shfl_xor(acc, 2, 64); acc = __fadd_rn(acc, o);
      o = __shfl_xor(acc, 4, 64); acc = __fadd_rn(acc, o);
      o = __shfl_xor(acc, 8, 64); acc = __fadd_rn(acc, o);
      if (lane == 0) xnr[r] = acc;
    }
    __syncthreads();

    float d[4][RGRP];
    #pragma unroll
    for (int c4 = 0; c4 < 4; ++c4)
      #pragma unroll
      for (int r = 0; r < RGRP; ++r) d[c4][r] = 0.0f;

    // ---- prefetched dot loop (validated R7): e_cur consumed while e_nxt in flight.
    float e_cur[4][4], e_nxt[4][4];
    #pragma unroll
    for (int kk = 0; kk < 4; ++kk)
      #pragma unroll
      for (int c4 = 0; c4 < 4; ++c4)
        e_cur[kk][c4] = embT[(size_t)kk * 1024 + c4 * 256 + tid];

    for (int k0 = 0; k0 < DDIM; k0 += 4) {
      if (k0 + 4 < DDIM) {
        #pragma unroll
        for (int kk = 0; kk < 4; ++kk)
          #pragma unroll
          for (int c4 = 0; c4 < 4; ++c4)
            e_nxt[kk][c4] = embT[(size_t)(k0 + 4 + kk) * 1024 + c4 * 256 + tid];
      }
      #pragma unroll
      for (int r = 0; r < RGRP; ++r) {
        float4 xv = *(const float4*)&xs[r][k0];
        #pragma unroll
        for (int c4 = 0; c4 < 4; ++c4) {
          d[c4][r] = fmaf(xv.x, e_cur[0][c4], d[c4][r]);
          d[c4][r] = fmaf(xv.y, e_cur[1][c4], d[c4][r]);
          d[c4][r] = fmaf(xv.z, e_cur[2][c4], d[c4][r]);
          d[c4][r] = fmaf(xv.w, e_cur[3][c4], d[c4][r]);
        }
      }
      #pragma unroll
      for (int kk = 0; kk < 4; ++kk)
        #pragma unroll
        for (int c4 = 0; c4 < 4; ++c4)
          e_cur[kk][c4] = e_nxt[kk][c4];
    }

    float b[RGRP]; int bi[RGRP];
    #pragma unroll
    for (int r = 0; r < RGRP; ++r) { b[r] = 3.4e38f; bi[r] = 0; }
    #pragma unroll
    for (int c4 = 0; c4 < 4; ++c4) {
      int m = c4 * 256 + tid;
      float en = enorm[m];
      #pragma unroll
      for (int r = 0; r < RGRP; ++r) {
        float T = __fadd_rn(en, xnr[r]);
        float s = __fadd_rn(T, __fmul_rn(-2.0f, d[c4][r]));
        if (s < b[r] || (s == b[r] && m < bi[r])) { b[r] = s; bi[r] = m; }
      }
    }
    #pragma unroll
    for (int r = 0; r < RGRP; ++r) { rv[r][tid] = b[r]; ri[r][tid] = bi[r]; }
    __syncthreads();
    for (int st = 128; st > 0; st >>= 1) {
      if (tid < st) {
        #pragma unroll
        for (int r = 0; r < RGRP; ++r) {
          float v = rv[r][tid + st]; int m2 = ri[r][tid + st];
          if (v < rv[r][tid] || (v == rv[r][tid] && m2 < ri[r][tid])) { rv[r][tid] = v; ri[r][tid] = m2; }
        }
      }
      __syncthreads();
    }

    // ---- parallel output tail (validated R7). Winners out, rv/ri reused as scratch.
    if (tid < RGRP) sbf[tid] = ri[tid][0];
    __syncthreads();

    float* laf = (float*)ri;   // ri storage reused for |x| partials
    #pragma unroll
    for (int r = 0; r < RGRP; ++r) {
      int bf = sbf[r];
      float xv = xs[r][tid];
      float ev = emb[(size_t)bf * DDIM + tid];   // 16 independent loads in flight
      if (r < cnt) {
        float q = __fadd_rn(xv, __fadd_rn(ev, -xv));
        qout[(size_t)rown[r] * DDIM + tid] = q;
      }
      float dd = xv - ev;
      rv[r][tid] = dd * dd;                      // same per-row partials as validated
      laf[r * 256 + tid] = fabsf(xv);
    }
    __syncthreads();
    for (int st = 128; st > 0; st >>= 1) {
      if (tid < st) {
        #pragma unroll
        for (int r = 0; r < RGRP; ++r) {
          rv[r][tid] += rv[r][tid + st];         // identical pairwise tree per row
          laf[r * 256 + tid] += laf[r * 256 + tid + st];
        }
      }
      __syncthreads();
    }
    if (tid < cnt) {
      int bfin = sbf[tid];
      int row = rown[tid];
      float np = (laf[tid * 256] > 0.0f) ? 1.0f : 0.0f;
      atomicAdd(&loss_extra[0], (rv[tid][0] * (1.0f / 256.0f)) * np);
      atomicAdd(&loss_extra[1], np);
      atomicAdd(&counts[bfin], 1.0f);
      idx_out[row] = bfin;
      out_idxf[row] = (float)bfin;
    }
  }
}

// ---------------- Kernel 4: finalize loss + perplexity ----------------
__global__ __launch_bounds__(256)
void finalize_kernel(const float* __restrict__ counts,
                     const float* __restrict__ loss_part, const float* __restrict__ np_part,
                     const float* __restrict__ loss_extra,
                     float* __restrict__ out_loss, float* __restrict__ out_perp) {
  __shared__ float red[768];
  int t = threadIdx.x;
  float esum = 0.0f, lsum = 0.0f, nsum = 0.0f;
  for (int m = t; m < MCODES; m += 256) {
    float p = counts[m] * (1.0f / 65536.0f);
    esum += p * logf(p + 1e-10f);
  }
  for (int i = t; i < NPART; i += 256) {
    lsum += loss_part[i];
    nsum += np_part[i];
  }
  red[t] = esum; red[256 + t] = lsum; red[512 + t] = nsum;
  __syncthreads();
  for (int s = 128; s > 0; s >>= 1) {
    if (t < s) {
      red[t] += red[t + s];
      red[256 + t] += red[256 + t + s];
      red[512 + t] += red[512 + t + s];
    }
    __syncthreads();
  }
  if (t == 0) {
    *out_perp = expf(-red[0]);
    float ls = red[256] + loss_extra[0];
    float ns = red[512] + loss_extra[1];
    *out_loss = 0.25f * ls / ns;
  }
}

extern "C" void kernel_launch(void* const* d_in, const int* in_sizes, int n_in,
                              void* d_out, int out_size, void* d_ws, size_t ws_size,
                              hipStream_t stream) {
  (void)in_sizes; (void)n_in; (void)out_size; (void)ws_size;
  const float* x = (const float*)d_in[0];
  const float* emb = (const float*)d_in[1];

  float* out = (float*)d_out;
  float* qst = out;                   // 16777216
  float* out_loss = out + 16777216;   // 1
  float* out_idxf = out + 16777217;   // 65536
  float* out_perp = out + 16842753;   // 1

  float* ws = (float*)d_ws;
  float* enorm = ws;                        // 1024
  int* idx = (int*)(ws + 1024);             // 65536
  float* counts = ws + 66560;               // 1024
  float* lpart = ws + 67584;                // 1024
  float* npart = ws + 68608;                // 1024
  float* loss_extra = ws + 69632;           // 2
  int* nflag = (int*)(ws + 69634);          // 1
  int* flist = (int*)(ws + 69636);          // 65536
  unsigned short* eimg = (unsigned short*)(ws + 135172);  // 512 KB (262144 ushort), 16B-aligned
  float* embT = ws + 266244;                // 1 MB (262144 floats)

  prep_kernel<<<448, 256, 0, stream>>>(emb, enorm, counts, nflag, loss_extra, eimg, embT);
  score_kernel<<<1024, 256, 0, stream>>>(x, emb, enorm, eimg, idx, out_idxf,
                                         qst, counts, lpart, npart, nflag, flist);
  rescore_kernel<<<1024, 256, 0, stream>>>(x, emb, embT, enorm, idx, out_idxf,
                                           qst, counts, loss_extra, nflag, flist);
  finalize_kernel<<<1, 256, 0, stream>>>(counts, lpart, npart, loss_extra, out_loss, out_perp);
}

// Round 14
// 223.694 us; speedup vs baseline: 1.1510x; 1.1510x over previous
//
#include <hip/hip_runtime.h>

#define BROWS 65536
#define DDIM 256
#define MCODES 1024
// Margin budget (xn-free f16 epilogue vs reference):
//   deterministic ref rounding noise <= 2*ulp(256) = 6.1e-5
//   f16 1-pass dot-pair noise sigma ~ 2.5e-5  ->  3e-4 gives ~10 sigma slack.
// Measured (R5): ~1500-2000 flagged rows at 3e-4.
#define FLAG_MARGIN 3e-4f
#define RGRP 8
#define NPART 1024

typedef __attribute__((ext_vector_type(8))) _Float16 h8f16;   // f16x8 MFMA frag
typedef __attribute__((ext_vector_type(4))) float float4v;    // fp32x4 acc

__device__ inline unsigned short f2h_bits(float f) {
  union { _Float16 h; unsigned short u; } cv;
  cv.h = (_Float16)f;   // v_cvt_f16_f32, RNE
  return cv.u;
}

// ---------------- Kernel 1: emb-only prep (VALIDATED R8) ----------------
__global__ __launch_bounds__(256)
void prep_kernel(const float* __restrict__ emb,
                 float* __restrict__ enorm,
                 float* __restrict__ counts, int* __restrict__ nflag,
                 float* __restrict__ loss_extra,
                 unsigned short* __restrict__ eimg, float* __restrict__ embT) {
  int b = blockIdx.x;
  int tid = threadIdx.x;
  if (b < 64) {
    int t = b * 256 + tid;            // [0, 16384) -> 1024 emb rows x 16 lanes
    if (t < MCODES) counts[t] = 0.0f;
    if (t == 0) *nflag = 0;
    if (t < 2) loss_extra[t] = 0.0f;
    int row = t >> 4;
    int lane = t & 15;
    const float* p = emb + (size_t)row * DDIM;
    int half = (lane >> 3) & 1;
    int j = lane & 7;
    const float* q = p + half * 128 + j;
    float v = q[0];
    float acc = __fmul_rn(v, v);
    #pragma unroll
    for (int i = 1; i < 16; ++i) {
      v = q[i * 8];
      acc = __fadd_rn(acc, __fmul_rn(v, v));
    }
    float o;
    o = __shfl_xor(acc, 1, 64); acc = __fadd_rn(acc, o);
    o = __shfl_xor(acc, 2, 64); acc = __fadd_rn(acc, o);
    o = __shfl_xor(acc, 4, 64); acc = __fadd_rn(acc, o);
    o = __shfl_xor(acc, 8, 64); acc = __fadd_rn(acc, o);
    if (lane == 0) enorm[row] = acc;
  } else if (b < 192) {
    // f16 image chunk t (16B): lane=t&63, tile=(t>>6)&1, kstep=(t>>7)&7, cc=t>>10.
    // code = cc*32 + tile*16 + (lane&15); k = kstep*32 + (lane>>4)*8 + j.
    // stores f16(256*e) — exact pow2 scale; epilogue multiplies by -2^-7.
    int t = (b - 64) * 256 + tid;     // [0, 32768)
    int lane = t & 63;
    int tile = (t >> 6) & 1;
    int kstep = (t >> 7) & 7;
    int cc = t >> 10;
    int code = cc * 32 + tile * 16 + (lane & 15);
    int kb = kstep * 32 + (lane >> 4) * 8;
    const float* src = emb + (size_t)code * DDIM + kb;
    union { unsigned short u[8]; uint4 v; } out;
    #pragma unroll
    for (int jj = 0; jj < 8; ++jj) out.u[jj] = f2h_bits(src[jj] * 256.0f);
    ((uint4*)eimg)[t] = out.v;
  } else {
    int t = (b - 192) * 256 + tid;    // [0, 65536)
    int base = t * 4;
    int k = base >> 10;
    int m = base & 1023;
    float4 v;
    v.x = emb[(size_t)(m + 0) * DDIM + k];
    v.y = emb[(size_t)(m + 1) * DDIM + k];
    v.z = emb[(size_t)(m + 2) * DDIM + k];
    v.w = emb[(size_t)(m + 3) * DDIM + k];
    *(float4*)&embT[base] = v;
  }
}

// ---------------- Kernel 2: 1-pass f16 score — R11 kernel VERBATIM (best measured: 88us) ----------------
// R13 falsified the barrier-free variant (105us): LDS staging + global_load_lds prefetch
// + barrier dbuf pipelines BETTER than direct L2 loads. Restored as-is.
__global__ __launch_bounds__(256, 4)
void score_kernel(const float* __restrict__ x, const float* __restrict__ emb,
                  const float* __restrict__ enorm_g,
                  const unsigned short* __restrict__ eimg,
                  int* __restrict__ idx_out, float* __restrict__ out_idxf,
                  float* __restrict__ qout, float* __restrict__ counts,
                  float* __restrict__ loss_part, float* __restrict__ np_part,
                  int* __restrict__ nflag, int* __restrict__ flist) {
  __shared__ __align__(16) unsigned short ebuf[2][8192];   // 2 x 16KB
  __shared__ float enorm_s[MCODES];
  __shared__ float sb1[2][64], sb2[2][64];
  __shared__ int si1[2][64];
  __shared__ int lcount;
  __shared__ int lbase;
  __shared__ int lrows[64];
  __shared__ int sidx[64];
  __shared__ unsigned char sflag[64];
  __shared__ float red[8];

  int tid = threadIdx.x;
  int w = tid >> 6;
  int lane = tid & 63;
  int quad = lane >> 4;
  int rowBase = blockIdx.x * 64;
  int waveRow = rowBase + (w & 1) * 32;   // rows this wave owns (32)
  int ct = w >> 1;                        // code-half this wave owns (16 codes)
  int rot = blockIdx.x & 31;              // per-block tile rotation

  if (tid == 0) lcount = 0;
  for (int i = tid; i < MCODES; i += 256) enorm_s[i] = enorm_g[i];

  // A-frag preload (validated layout): rows waveRow + rg*16 + (lane&15), k = ks*32 + quad*8 + j
  h8f16 xh[2][8];
  const float* xbase = x + (size_t)(waveRow + (lane & 15)) * DDIM + quad * 8;
  #pragma unroll
  for (int rg = 0; rg < 2; ++rg) {
    #pragma unroll
    for (int ks = 0; ks < 8; ++ks) {
      const float4* p = (const float4*)(xbase + rg * 16 * DDIM + ks * 32);
      float4 v0 = p[0], v1 = p[1];
      h8f16 h;
      h[0] = (_Float16)v0.x; h[1] = (_Float16)v0.y;
      h[2] = (_Float16)v0.z; h[3] = (_Float16)v0.w;
      h[4] = (_Float16)v1.x; h[5] = (_Float16)v1.y;
      h[6] = (_Float16)v1.z; h[7] = (_Float16)v1.w;
      xh[rg][ks] = h;
    }
  }

  float b1[2][4], b2[2][4];
  int i1[2][4];
  #pragma unroll
  for (int rg = 0; rg < 2; ++rg)
    #pragma unroll
    for (int reg = 0; reg < 4; ++reg) { b1[rg][reg] = 3.4e38f; b2[rg][reg] = 3.4e38f; i1[rg][reg] = 0; }

  // stage one tile chunk (8192 shorts = 16KB): wave w covers 2048 shorts, 4 insts of 1KB.
  #define STAGE_CC(ccv, bf) do { \
    const unsigned short* g_ = eimg + (size_t)(ccv) * 8192 + w * 2048 + lane * 8; \
    unsigned short* l_ = &ebuf[(bf)][w * 2048]; \
    _Pragma("unroll") \
    for (int j_ = 0; j_ < 4; ++j_) { \
      __builtin_amdgcn_global_load_lds((const __attribute__((address_space(1))) unsigned int*)(g_ + j_ * 512), \
                                       (__attribute__((address_space(3))) unsigned int*)(l_ + j_ * 512), 16, 0, 0); \
    } \
  } while (0)

  STAGE_CC(rot, 0);

  for (int cc = 0; cc < 32; ++cc) {
    int buf = cc & 1;
    int tc = (cc + rot) & 31;        // rotated tile index for this block
    __syncthreads();                 // stage(tc) visible; prev buf free
    if (cc < 31) STAGE_CC((tc + 1) & 31, buf ^ 1);

    float4v acc0 = (float4v){0.f, 0.f, 0.f, 0.f};   // rg = 0
    float4v acc1 = (float4v){0.f, 0.f, 0.f, 0.f};   // rg = 1
    #pragma unroll
    for (int ks = 0; ks < 8; ++ks) {
      h8f16 e = *(const h8f16*)&ebuf[buf][ks * 1024 + ct * 512 + lane * 8];
      acc0 = __builtin_amdgcn_mfma_f32_16x16x32_f16(xh[0][ks], e, acc0, 0, 0, 0);
      acc1 = __builtin_amdgcn_mfma_f32_16x16x32_f16(xh[1][ks], e, acc1, 0, 0, 0);
    }

    int m = tc * 32 + ct * 16 + (lane & 15);
    float en = enorm_s[m];
    #pragma unroll
    for (int rg = 0; rg < 2; ++rg)
      #pragma unroll
      for (int reg = 0; reg < 4; ++reg) {
        float av = rg ? acc1[reg] : acc0[reg];
        float s = __fadd_rn(en, __fmul_rn(-0.0078125f, av));   // -2*dot = acc * -2^-7, exact scale
        // branchless two-min (value-exact, validated R11)
        float nb1 = fminf(s, b1[rg][reg]);
        b2[rg][reg] = fminf(b2[rg][reg], fmaxf(s, b1[rg][reg]));
        i1[rg][reg] = (s < b1[rg][reg]) ? m : i1[rg][reg];
        b1[rg][reg] = nb1;
      }
  }

  // cross-lane argmin over the 16 cols of this wave's code-half (verbatim two-min merge)
  #pragma unroll
  for (int off = 1; off < 16; off <<= 1) {
    #pragma unroll
    for (int rg = 0; rg < 2; ++rg)
      #pragma unroll
      for (int reg = 0; reg < 4; ++reg) {
        float ob1 = __shfl_xor(b1[rg][reg], off, 64);
        float ob2 = __shfl_xor(b2[rg][reg], off, 64);
        int oi = __shfl_xor(i1[rg][reg], off, 64);
        float cb1 = b1[rg][reg], cb2 = b2[rg][reg];
        int ci = i1[rg][reg];
        float nb1, nb2; int ni;
        if (ob1 < cb1)      { nb1 = ob1; ni = oi; nb2 = fminf(cb1, ob2); }
        else if (cb1 < ob1) { nb1 = cb1; ni = ci; nb2 = fminf(ob1, cb2); }
        else                { nb1 = cb1; ni = min(ci, oi); nb2 = cb1; }  // tie -> flag
        b1[rg][reg] = nb1; b2[rg][reg] = nb2; i1[rg][reg] = ni;
      }
  }

  // per-wave results -> LDS (row-half x code-half)
  if ((lane & 15) == 0) {
    #pragma unroll
    for (int rg = 0; rg < 2; ++rg)
      #pragma unroll
      for (int reg = 0; reg < 4; ++reg) {
        int lr = (w & 1) * 32 + rg * 16 + quad * 4 + reg;
        sb1[ct][lr] = b1[rg][reg];
        sb2[ct][lr] = b2[rg][reg];
        si1[ct][lr] = i1[rg][reg];
      }
  }
  __syncthreads();

  // cross-half merge (same two-min semantics: winner's b2 vs loser's b1; eq -> tie/flag)
  if (tid < 64) {
    float a1 = sb1[0][tid], a2 = sb2[0][tid];
    float c1 = sb1[1][tid], c2 = sb2[1][tid];
    int ia = si1[0][tid], ic = si1[1][tid];
    float f1, f2; int fi;
    if (a1 < c1)      { f1 = a1; fi = ia; f2 = fminf(a2, c1); }
    else if (c1 < a1) { f1 = c1; fi = ic; f2 = fminf(c2, a1); }
    else              { f1 = a1; fi = min(ia, ic); f2 = a1; }   // tie -> flag
    int row = rowBase + tid;
    idx_out[row] = fi;
    out_idxf[row] = (float)fi;
    sidx[tid] = fi;
    int fl = (__fadd_rn(f2, -f1) <= FLAG_MARGIN) ? 1 : 0;
    sflag[tid] = (unsigned char)fl;
    if (fl) {
      int pp = atomicAdd(&lcount, 1);
      lrows[pp] = row;
    }
  }
  __syncthreads();
  if (tid == 0 && lcount > 0) lbase = atomicAdd(nflag, lcount);
  __syncthreads();
  if (tid < lcount) flist[lbase + tid] = lrows[tid];

  // ---- fused gather (VALIDATED R9): ALL 4 waves, 16 sequential rows each.
  float lsum = 0.0f, nsum = 0.0f;
  for (int it = 0; it < 16; ++it) {
    int lr = w * 16 + it;
    int row = rowBase + lr;
    int id = sidx[lr];
    int fl = sflag[lr];
    float4 xv = ((const float4*)x)[(size_t)row * 64 + lane];
    float4 ev = ((const float4*)emb)[(size_t)id * 64 + lane];
    float4 q;
    q.x = __fadd_rn(xv.x, __fadd_rn(ev.x, -xv.x));
    q.y = __fadd_rn(xv.y, __fadd_rn(ev.y, -xv.y));
    q.z = __fadd_rn(xv.z, __fadd_rn(ev.z, -xv.z));
    q.w = __fadd_rn(xv.w, __fadd_rn(ev.w, -xv.w));
    ((float4*)qout)[(size_t)row * 64 + lane] = q;

    float d0 = xv.x - ev.x, d1 = xv.y - ev.y, d2 = xv.z - ev.z, d3 = xv.w - ev.w;
    float loc = d0 * d0 + d1 * d1 + d2 * d2 + d3 * d3;
    float la = fabsf(xv.x) + fabsf(xv.y) + fabsf(xv.z) + fabsf(xv.w);
    #pragma unroll
    for (int off = 32; off > 0; off >>= 1) {
      loc += __shfl_xor(loc, off, 64);
      la += __shfl_xor(la, off, 64);
    }
    if (lane == 0 && !fl) {
      float np = (la > 0.0f) ? 1.0f : 0.0f;
      lsum += (loc * (1.0f / 256.0f)) * np;
      nsum += np;
      atomicAdd(&counts[id], 1.0f);
    }
  }
  if (lane == 0) { red[w] = lsum; red[4 + w] = nsum; }
  __syncthreads();
  if (tid == 0) {
    loss_part[blockIdx.x] = (red[0] + red[1]) + (red[2] + red[3]);
    np_part[blockIdx.x] = (red[4] + red[5]) + (red[6] + red[7]);
  }
  #undef STAGE_CC
}

// ---------------- Kernel 3: exact fp32 rescore — R14: RGRP 16 -> 8 ----------------
// R13 accounting: rescore is the hidden ~70-120us (never re-measured since R5's 122us;
// ~125 working blocks = 1 wave/SIMD, zero TLP, 256 FMA/thread/iter serial chain).
// RGRP=8 doubles active blocks (~190-250) and halves per-thread FMA. Local-xnorm
// recompute keeps the EXACT 16-lane association (guarded tid<128; shfl within waves).
// Per-row FMA order, tie rule, and output trees unchanged -> bit-identical outputs.
__global__ __launch_bounds__(256)
void rescore_kernel(const float* __restrict__ x, const float* __restrict__ emb,
                    const float* __restrict__ embT,
                    const float* __restrict__ enorm,
                    int* __restrict__ idx_out, float* __restrict__ out_idxf,
                    float* __restrict__ qout, float* __restrict__ counts,
                    float* __restrict__ loss_extra,
                    const int* __restrict__ nflag, const int* __restrict__ flist) {
  __shared__ float xs[RGRP][DDIM];
  __shared__ float xnr[RGRP];
  __shared__ int rown[RGRP];
  __shared__ int sbf[RGRP];
  __shared__ float rv[RGRP][256];
  __shared__ int ri[RGRP][256];
  int tid = threadIdx.x;
  int n = nflag[0];

  for (int g = blockIdx.x; g * RGRP < n; g += 1024) {
    int base = g * RGRP;
    int cnt = min(RGRP, n - base);
    __syncthreads();
    if (tid < RGRP) {
      int rr = flist[base + min(tid, cnt - 1)];
      rown[tid] = rr;
    }
    __syncthreads();
    #pragma unroll
    for (int r = 0; r < RGRP; ++r) xs[r][tid] = x[(size_t)rown[r] * DDIM + tid];
    __syncthreads();

    // local xnorm: rows 0..RGRP-1 handled by threads 0..RGRP*16-1 (16 lanes/row) —
    // EXACT association of the validated norms kernel (16 strided squares, shfl 1,2,4,8).
    if (tid < RGRP * 16) {
      int r = tid >> 4;
      int lane = tid & 15;
      int half = (lane >> 3) & 1;
      int j = lane & 7;
      const float* q = &xs[r][half * 128 + j];
      float v = q[0];
      float acc = __fmul_rn(v, v);
      #pragma unroll
      for (int i = 1; i < 16; ++i) {
        v = q[i * 8];
        acc = __fadd_rn(acc, __fmul_rn(v, v));
      }
      float o;
      o = __shfl_xor(acc, 1, 64); acc = __fadd_rn(acc, o);
      o = __shfl_xor(acc, 2, 64); acc = __fadd_rn(acc, o);
      o = __shfl_xor(acc, 4, 64); acc = __fadd_rn(acc, o);
      o = __shfl_xor(acc, 8, 64); acc = __fadd_rn(acc, o);
      if (lane == 0) xnr[r] = acc;
    }
    __syncthreads();

    float d[4][RGRP];
    #pragma unroll
    for (int c4 = 0; c4 < 4; ++c4)
      #pragma unroll
      for (int r = 0; r < RGRP; ++r) d[c4][r] = 0.0f;

    // ---- prefetched dot loop (validated R7): e_cur consumed while e_nxt in flight.
    float e_cur[4][4], e_nxt[4][4];
    #pragma unroll
    for (int kk = 0; kk < 4; ++kk)
      #pragma unroll
      for (int c4 = 0; c4 < 4; ++c4)
        e_cur[kk][c4] = embT[(size_t)kk * 1024 + c4 * 256 + tid];

    for (int k0 = 0; k0 < DDIM; k0 += 4) {
      if (k0 + 4 < DDIM) {
        #pragma unroll
        for (int kk = 0; kk < 4; ++kk)
          #pragma unroll
          for (int c4 = 0; c4 < 4; ++c4)
            e_nxt[kk][c4] = embT[(size_t)(k0 + 4 + kk) * 1024 + c4 * 256 + tid];
      }
      #pragma unroll
      for (int r = 0; r < RGRP; ++r) {
        float4 xv = *(const float4*)&xs[r][k0];
        #pragma unroll
        for (int c4 = 0; c4 < 4; ++c4) {
          d[c4][r] = fmaf(xv.x, e_cur[0][c4], d[c4][r]);
          d[c4][r] = fmaf(xv.y, e_cur[1][c4], d[c4][r]);
          d[c4][r] = fmaf(xv.z, e_cur[2][c4], d[c4][r]);
          d[c4][r] = fmaf(xv.w, e_cur[3][c4], d[c4][r]);
        }
      }
      #pragma unroll
      for (int kk = 0; kk < 4; ++kk)
        #pragma unroll
        for (int c4 = 0; c4 < 4; ++c4)
          e_cur[kk][c4] = e_nxt[kk][c4];
    }

    float b[RGRP]; int bi[RGRP];
    #pragma unroll
    for (int r = 0; r < RGRP; ++r) { b[r] = 3.4e38f; bi[r] = 0; }
    #pragma unroll
    for (int c4 = 0; c4 < 4; ++c4) {
      int m = c4 * 256 + tid;
      float en = enorm[m];
      #pragma unroll
      for (int r = 0; r < RGRP; ++r) {
        float T = __fadd_rn(en, xnr[r]);
        float s = __fadd_rn(T, __fmul_rn(-2.0f, d[c4][r]));
        if (s < b[r] || (s == b[r] && m < bi[r])) { b[r] = s; bi[r] = m; }
      }
    }
    #pragma unroll
    for (int r = 0; r < RGRP; ++r) { rv[r][tid] = b[r]; ri[r][tid] = bi[r]; }
    __syncthreads();
    for (int st = 128; st > 0; st >>= 1) {
      if (tid < st) {
        #pragma unroll
        for (int r = 0; r < RGRP; ++r) {
          float v = rv[r][tid + st]; int m2 = ri[r][tid + st];
          if (v < rv[r][tid] || (v == rv[r][tid] && m2 < ri[r][tid])) { rv[r][tid] = v; ri[r][tid] = m2; }
        }
      }
      __syncthreads();
    }

    // ---- parallel output tail (validated R7). Winners out, rv/ri reused as scratch.
    if (tid < RGRP) sbf[tid] = ri[tid][0];
    __syncthreads();

    float* laf = (float*)ri;   // ri storage reused for |x| partials
    #pragma unroll
    for (int r = 0; r < RGRP; ++r) {
      int bf = sbf[r];
      float xv = xs[r][tid];
      float ev = emb[(size_t)bf * DDIM + tid];   // RGRP independent loads in flight
      if (r < cnt) {
        float q = __fadd_rn(xv, __fadd_rn(ev, -xv));
        qout[(size_t)rown[r] * DDIM + tid] = q;
      }
      float dd = xv - ev;
      rv[r][tid] = dd * dd;                      // same per-row partials as validated
      laf[r * 256 + tid] = fabsf(xv);
    }
    __syncthreads();
    for (int st = 128; st > 0; st >>= 1) {
      if (tid < st) {
        #pragma unroll
        for (int r = 0; r < RGRP; ++r) {
          rv[r][tid] += rv[r][tid + st];         // identical pairwise tree per row
          laf[r * 256 + tid] += laf[r * 256 + tid + st];
        }
      }
      __syncthreads();
    }
    if (tid < cnt) {
      int bfin = sbf[tid];
      int row = rown[tid];
      float np = (laf[tid * 256] > 0.0f) ? 1.0f : 0.0f;
      atomicAdd(&loss_extra[0], (rv[tid][0] * (1.0f / 256.0f)) * np);
      atomicAdd(&loss_extra[1], np);
      atomicAdd(&counts[bfin], 1.0f);
      idx_out[row] = bfin;
      out_idxf[row] = (float)bfin;
    }
  }
}

// ---------------- Kernel 4: finalize loss + perplexity ----------------
__global__ __launch_bounds__(256)
void finalize_kernel(const float* __restrict__ counts,
                     const float* __restrict__ loss_part, const float* __restrict__ np_part,
                     const float* __restrict__ loss_extra,
                     float* __restrict__ out_loss, float* __restrict__ out_perp) {
  __shared__ float red[768];
  int t = threadIdx.x;
  float esum = 0.0f, lsum = 0.0f, nsum = 0.0f;
  for (int m = t; m < MCODES; m += 256) {
    float p = counts[m] * (1.0f / 65536.0f);
    esum += p * logf(p + 1e-10f);
  }
  for (int i = t; i < NPART; i += 256) {
    lsum += loss_part[i];
    nsum += np_part[i];
  }
  red[t] = esum; red[256 + t] = lsum; red[512 + t] = nsum;
  __syncthreads();
  for (int s = 128; s > 0; s >>= 1) {
    if (t < s) {
      red[t] += red[t + s];
      red[256 + t] += red[256 + t + s];
      red[512 + t] += red[512 + t + s];
    }
    __syncthreads();
  }
  if (t == 0) {
    *out_perp = expf(-red[0]);
    float ls = red[256] + loss_extra[0];
    float ns = red[512] + loss_extra[1];
    *out_loss = 0.25f * ls / ns;
  }
}

extern "C" void kernel_launch(void* const* d_in, const int* in_sizes, int n_in,
                              void* d_out, int out_size, void* d_ws, size_t ws_size,
                              hipStream_t stream) {
  (void)in_sizes; (void)n_in; (void)out_size; (void)ws_size;
  const float* x = (const float*)d_in[0];
  const float* emb = (const float*)d_in[1];

  float* out = (float*)d_out;
  float* qst = out;                   // 16777216
  float* out_loss = out + 16777216;   // 1
  float* out_idxf = out + 16777217;   // 65536
  float* out_perp = out + 16842753;   // 1

  float* ws = (float*)d_ws;
  float* enorm = ws;                        // 1024
  int* idx = (int*)(ws + 1024);             // 65536
  float* counts = ws + 66560;               // 1024
  float* lpart = ws + 67584;                // 1024
  float* npart = ws + 68608;                // 1024
  float* loss_extra = ws + 69632;           // 2
  int* nflag = (int*)(ws + 69634);          // 1
  int* flist = (int*)(ws + 69636);          // 65536
  unsigned short* eimg = (unsigned short*)(ws + 135172);  // 512 KB (262144 ushort), 16B-aligned
  float* embT = ws + 266244;                // 1 MB (262144 floats)

  prep_kernel<<<448, 256, 0, stream>>>(emb, enorm, counts, nflag, loss_extra, eimg, embT);
  score_kernel<<<1024, 256, 0, stream>>>(x, emb, enorm, eimg, idx, out_idxf,
                                         qst, counts, lpart, npart, nflag, flist);
  rescore_kernel<<<1024, 256, 0, stream>>>(x, emb, embT, enorm, idx, out_idxf,
                                           qst, counts, loss_extra, nflag, flist);
  finalize_kernel<<<1, 256, 0, stream>>>(counts, lpart, npart, loss_extra, out_loss, out_perp);
}